// Round 11
// baseline (154.188 us; speedup 1.0000x reference)
//
#include <hip/hip_runtime.h>
#include <hip/hip_bf16.h>

// MultiHeadSelfAttention: B=2, S=2048, D=1024, H=16, DK=64
// cast -> QKV gemm -> transpose V -> flash attention (swapped-QKT, 4-wave kv-split TLP) -> out-proj gemm

typedef __attribute__((ext_vector_type(4))) float f32x4;
typedef __attribute__((ext_vector_type(16))) float f32x16;
typedef __attribute__((ext_vector_type(8))) short bf16x8;

#if defined(__has_builtin)
#if __has_builtin(__builtin_amdgcn_permlane32_swap)
#define HAVE_PL32 1
#endif
#endif

__device__ __forceinline__ unsigned short f2bf(float f) {
  unsigned int u = __float_as_uint(f);
  u += 0x7fffu + ((u >> 16) & 1u);
  return (unsigned short)(u >> 16);
}

__device__ __forceinline__ unsigned int cvtpk_bf16(float lo, float hi) {
  unsigned int r;
  asm("v_cvt_pk_bf16_f32 %0, %1, %2" : "=v"(r) : "v"(lo), "v"(hi));
  return r;
}

// max(own, partner-at-lane^32): swap(a,b) -> r0={a_lo,b_lo}, r1={a_hi,b_hi}
__device__ __forceinline__ float plmax32(float x) {
#ifdef HAVE_PL32
  auto r = __builtin_amdgcn_permlane32_swap(__float_as_uint(x), __float_as_uint(x), false, false);
  return fmaxf(__uint_as_float(r[0]), __uint_as_float(r[1]));
#else
  return fmaxf(x, __shfl_xor(x, 32));
#endif
}

__global__ void cast_f32_bf16(const float* __restrict__ src,
                              unsigned short* __restrict__ dst, int n4) {
  int i = blockIdx.x * blockDim.x + threadIdx.x;
  if (i >= n4) return;
  float4 v = ((const float4*)src)[i];
  ushort4 o = make_ushort4(f2bf(v.x), f2bf(v.y), f2bf(v.z), f2bf(v.w));
  ((ushort4*)dst)[i] = o;
}

__global__ void cast_w(const float* __restrict__ Wq, const float* __restrict__ Wk,
                       const float* __restrict__ Wv, const float* __restrict__ Wo,
                       unsigned short* __restrict__ Wqkvb, unsigned short* __restrict__ Wob,
                       int nw4) {
  int i = blockIdx.x * blockDim.x + threadIdx.x;
  int sel = i / nw4, r = i - sel * nw4;
  if (sel >= 4) return;
  const float* src = (sel == 0) ? Wq : (sel == 1) ? Wk : (sel == 2) ? Wv : Wo;
  unsigned short* dst = (sel < 3) ? (Wqkvb + (size_t)sel * 1024 * 1024) : Wob;
  float4 v = ((const float4*)src)[r];
  ushort4 o = make_ushort4(f2bf(v.x), f2bf(v.y), f2bf(v.z), f2bf(v.w));
  ((ushort4*)dst)[r] = o;
}

typedef __attribute__((address_space(1))) const void gas_t;
typedef __attribute__((address_space(3))) void las_t;

__device__ __forceinline__ void gld_lds16(const unsigned short* g, unsigned short* l) {
  __builtin_amdgcn_global_load_lds((gas_t*)g, (las_t*)l, 16, 0, 0);
}

// C = A (M,K) * B(N,K)^T ; bf16 in, bf16 or f32 out. m97 structure.
template<bool BF16OUT>
__global__ __launch_bounds__(256)
void gemm_bt(const unsigned short* __restrict__ A, const unsigned short* __restrict__ B,
             void* __restrict__ Cv, int M, int N, int K) {
  __shared__ unsigned short As[128 * 32];
  __shared__ unsigned short Bs[128 * 32];
  const int tid = threadIdx.x;
  const int lane = tid & 63;
  const int wid = tid >> 6;
  const int wr = wid >> 1, wc = wid & 1;
  const int lr = lane & 15, lg = lane >> 4;
  const int m0 = blockIdx.x * 128, n0 = blockIdx.y * 128;

  f32x4 acc[4][4] = {};

  const int srow = tid >> 2;
  const int scol = (tid & 3) * 8;
  const unsigned short* Ag = A + (size_t)(m0 + srow) * K + scol;
  const unsigned short* Bg = B + (size_t)(n0 + srow) * K + scol;
  unsigned short* Al = &As[tid * 8];
  unsigned short* Bl = &Bs[tid * 8];

  for (int k0 = 0; k0 < K; k0 += 32) {
    gld_lds16(Ag + k0, Al);
    gld_lds16(Ag + k0 + (size_t)64 * K, Al + 2048);
    gld_lds16(Bg + k0, Bl);
    gld_lds16(Bg + k0 + (size_t)64 * K, Bl + 2048);
    asm volatile("s_waitcnt vmcnt(0)" ::: "memory");
    __syncthreads();

    bf16x8 af[4], bfr[4];
#pragma unroll
    for (int i = 0; i < 4; ++i)
      af[i] = *(const bf16x8*)&As[(wr * 64 + i * 16 + lr) * 32 + lg * 8];
#pragma unroll
    for (int j = 0; j < 4; ++j)
      bfr[j] = *(const bf16x8*)&Bs[(wc * 64 + j * 16 + lr) * 32 + lg * 8];
#pragma unroll
    for (int i = 0; i < 4; ++i)
#pragma unroll
      for (int j = 0; j < 4; ++j)
        acc[i][j] = __builtin_amdgcn_mfma_f32_16x16x32_bf16(af[i], bfr[j], acc[i][j], 0, 0, 0);
    __syncthreads();
  }

#pragma unroll
  for (int i = 0; i < 4; ++i) {
    const int row = m0 + wr * 64 + i * 16 + lg * 4;
#pragma unroll
    for (int j = 0; j < 4; ++j) {
      const int col = n0 + wc * 64 + j * 16 + lr;
#pragma unroll
      for (int r = 0; r < 4; ++r) {
        float v = acc[i][j][r];
        size_t idx = (size_t)(row + r) * N + col;
        if (BF16OUT) ((unsigned short*)Cv)[idx] = f2bf(v);
        else         ((float*)Cv)[idx] = v;
      }
    }
  }
}

// VT[(bh*64 + d)*2048 + s] = QKV[(b*2048+s)*3072 + 2048 + h*64 + d]
__global__ __launch_bounds__(256)
void transpose_v(const unsigned short* __restrict__ QKV, unsigned short* __restrict__ VT) {
  __shared__ __align__(16) unsigned short t[64 * 64];
  const int tid = threadIdx.x;
  const int bh = blockIdx.y, b = bh >> 4, h = bh & 15;
  const int s0 = blockIdx.x * 64;
#pragma unroll
  for (int it = 0; it < 2; ++it) {
    int idx = it * 256 + tid;
    int r = idx >> 3, c8 = (idx & 7) * 8;
    bf16x8 v = *(const bf16x8*)(QKV + (size_t)(b * 2048 + s0 + r) * 3072 + 2048 + h * 64 + c8);
    int sw = ((r & 7) ^ ((r >> 3) & 7)) * 8;
    *(bf16x8*)&t[r * 64 + (c8 ^ sw)] = v;
  }
  __syncthreads();
#pragma unroll
  for (int it = 0; it < 2; ++it) {
    int idx = it * 256 + tid;
    int d = idx >> 3, s8 = (idx & 7) * 8;
    unsigned short tmp[8];
#pragma unroll
    for (int j = 0; j < 8; ++j) {
      int row = s8 + j;
      int sw = ((row & 7) ^ ((row >> 3) & 7)) * 8;
      tmp[j] = t[row * 64 + ((d & ~7) ^ sw) + (d & 7)];
    }
    *(bf16x8*)(VT + (size_t)(bh * 64 + d) * 2048 + s0 + s8) = *(bf16x8*)tmp;
  }
}

// Flash attention, causal, swapped-QKT 32x32, 4-WAVE KV-SPLIT (TLP over ILP).
// Grid 1024 = 32 pairs x 32 bh; block = 4 waves, each takes a contiguous 1/4
// of the kv range -> 4096 waves = 4/SIMD at VGPR<=128 (launch_bounds(256,4)).
// No prefetch/pipeline: lean registers, latency hidden by wave interleave.
// Waves 1-3 post partials (o, M, L) in LDS; wave 0 merges + writes.
__global__ __launch_bounds__(256, 4)
void attn11(const unsigned short* __restrict__ QKV, const unsigned short* __restrict__ VT,
            unsigned short* __restrict__ O) {
  const int tid = threadIdx.x;
  const int w = tid >> 6;
  const int lane = tid & 63;
  const int l31 = lane & 31;
  const int hi = lane >> 5;
  const int blk = blockIdx.x;
  const int pair = blk >> 5;  // 0..31
  const int bh = blk & 31;
  const int b = bh >> 4, h = bh & 15;

  __shared__ float obuf[3][32][64];   // waves 1..3 O partials (row q, col d)
  __shared__ float ml[4][2][32];      // [wave][M/L][row]

  const unsigned short* Qb = QKV + (size_t)b * 2048 * 3072 + h * 64;
  const unsigned short* Kb = QKV + (size_t)b * 2048 * 3072 + 1024 + h * 64;
  const unsigned short* Vt = VT + (size_t)bh * 64 * 2048;

  const float sc = 0.125f * 1.44269504088896f;  // 1/sqrt(64) * log2(e)

  for (int ph = 0; ph < 2; ++ph) {
    const int qp = ph ? (63 - pair) : pair;
    const int nt = qp + 1;              // kv tiles of 32
    const int t0 = (nt * w) >> 2;
    const int t1 = (nt * (w + 1)) >> 2; // wave 3 always owns the diagonal

    bf16x8 qf[4];
#pragma unroll
    for (int i = 0; i < 4; ++i)
      qf[i] = *(const bf16x8*)(Qb + (size_t)(qp * 32 + l31) * 3072 + 16 * i + 8 * hi);

    f32x16 o0, o1;
#pragma unroll
    for (int r = 0; r < 16; ++r) { o0[r] = 0.f; o1[r] = 0.f; }
    float M = -1e30f, Lp = 0.f;

    for (int t = t0; t < t1; ++t) {
      // --- load K tile frags (B-operand rows kv=l31, k-slice 8*hi+e) ---
      bf16x8 kf[4];
#pragma unroll
      for (int i = 0; i < 4; ++i)
        kf[i] = *(const bf16x8*)(Kb + (size_t)(t * 32 + l31) * 3072 + 16 * i + 8 * hi);
      // --- V frags (B-operand for PV) ---
      bf16x8 vf[2][2];
#pragma unroll
      for (int c = 0; c < 2; ++c)
#pragma unroll
        for (int dh = 0; dh < 2; ++dh)
          vf[c][dh] = *(const bf16x8*)(Vt + (size_t)(dh * 32 + l31) * 2048 + t * 32 + c * 16 + 8 * hi);

      // --- S^T = K Q^T ---
      f32x16 st;
#pragma unroll
      for (int r = 0; r < 16; ++r) st[r] = 0.f;
      __builtin_amdgcn_s_setprio(1);
#pragma unroll
      for (int i = 0; i < 4; ++i)
        st = __builtin_amdgcn_mfma_f32_32x32x16_bf16(kf[i], qf[i], st, 0, 0, 0);
      __builtin_amdgcn_s_setprio(0);

      // --- scale (+ causal mask on diagonal), log2 domain ---
      float x[16];
#pragma unroll
      for (int r = 0; r < 16; ++r) x[r] = st[r] * sc;
      if (t == nt - 1) {
#pragma unroll
        for (int r = 0; r < 16; ++r) {
          int kvi = (r & 3) + 8 * (r >> 2) + 4 * hi;
          if (kvi > l31) x[r] = -3.0e38f;
        }
      }

      // --- row max + defer-max (THR=8) ---
      float mx = x[0];
#pragma unroll
      for (int r = 1; r < 16; ++r) mx = fmaxf(mx, x[r]);
      mx = plmax32(mx);
      bool chg = mx > M + 8.0f;
      if (__any(chg)) {
        float Mn = chg ? mx : M;
        float ef = exp2f(M - Mn);
        M = Mn;
        Lp *= ef;
#pragma unroll
        for (int r = 0; r < 16; ++r) {
          int qr = (r & 3) + 8 * (r >> 2) + 4 * hi;
          float efb = __shfl(ef, qr);
          o0[r] *= efb;
          o1[r] *= efb;
        }
      }

      // --- P = exp2(x - M); lane-partial L ---
      float p[16];
      float rs = 0.f;
#pragma unroll
      for (int r = 0; r < 16; ++r) {
        p[r] = exp2f(x[r] - M);
        rs += p[r];
      }
      Lp += rs;

      // --- pack P; assemble PV A-frags; PV ---
      unsigned int pw[8];
#pragma unroll
      for (int g = 0; g < 4; ++g) {
        pw[2 * g]     = cvtpk_bf16(p[4 * g],     p[4 * g + 1]);
        pw[2 * g + 1] = cvtpk_bf16(p[4 * g + 2], p[4 * g + 3]);
      }
#pragma unroll
      for (int c = 0; c < 2; ++c) {
        unsigned int a0 = pw[4 * c], a1 = pw[4 * c + 1];
        unsigned int b0 = pw[4 * c + 2], b1 = pw[4 * c + 3];
        union { unsigned int u[4]; bf16x8 v; } af;
#ifdef HAVE_PL32
        auto r0 = __builtin_amdgcn_permlane32_swap(a0, b0, false, false);
        auto r1 = __builtin_amdgcn_permlane32_swap(a1, b1, false, false);
        af.u[0] = r0[0]; af.u[2] = r0[1];
        af.u[1] = r1[0]; af.u[3] = r1[1];
#else
        unsigned int sa0 = __shfl_xor(a0, 32), sa1 = __shfl_xor(a1, 32);
        unsigned int sb0 = __shfl_xor(b0, 32), sb1 = __shfl_xor(b1, 32);
        af.u[0] = hi ? sb0 : a0;
        af.u[1] = hi ? sb1 : a1;
        af.u[2] = hi ? b0  : sa0;
        af.u[3] = hi ? b1  : sa1;
#endif
        __builtin_amdgcn_s_setprio(1);
        o0 = __builtin_amdgcn_mfma_f32_32x32x16_bf16(af.v, vf[c][0], o0, 0, 0, 0);
        o1 = __builtin_amdgcn_mfma_f32_32x32x16_bf16(af.v, vf[c][1], o1, 0, 0, 0);
        __builtin_amdgcn_s_setprio(0);
      }
    }

    // --- post partials / merge ---
    float Ltot = Lp + __shfl_xor(Lp, 32);
    if (!hi) { ml[w][0][l31] = M; ml[w][1][l31] = Ltot; }
    if (w != 0) {
#pragma unroll
      for (int r = 0; r < 16; ++r) {
        int qr = (r & 3) + 8 * (r >> 2) + 4 * hi;
        obuf[w - 1][qr][l31]      = o0[r];
        obuf[w - 1][qr][32 + l31] = o1[r];
      }
    }
    __syncthreads();
    if (w == 0) {
#pragma unroll
      for (int r = 0; r < 16; ++r) {
        int qr = (r & 3) + 8 * (r >> 2) + 4 * hi;
        float M0 = ml[0][0][qr], M1 = ml[1][0][qr];
        float M2 = ml[2][0][qr], M3 = ml[3][0][qr];
        float Mx = fmaxf(fmaxf(M0, M1), fmaxf(M2, M3));
        float e0 = exp2f(M0 - Mx), e1 = exp2f(M1 - Mx);
        float e2 = exp2f(M2 - Mx), e3 = exp2f(M3 - Mx);
        float L = ml[0][1][qr] * e0 + ml[1][1][qr] * e1 +
                  ml[2][1][qr] * e2 + ml[3][1][qr] * e3;
        float inv = 1.0f / L;
        float v0 = o0[r] * e0 + obuf[0][qr][l31] * e1 +
                   obuf[1][qr][l31] * e2 + obuf[2][qr][l31] * e3;
        float v1 = o1[r] * e0 + obuf[0][qr][32 + l31] * e1 +
                   obuf[1][qr][32 + l31] * e2 + obuf[2][qr][32 + l31] * e3;
        size_t base = (size_t)(b * 2048 + qp * 32 + qr) * 1024 + h * 64;
        O[base + l31]      = f2bf(v0 * inv);
        O[base + 32 + l31] = f2bf(v1 * inv);
      }
    }
    __syncthreads();  // LDS safe for next phase
  }
}

extern "C" void kernel_launch(void* const* d_in, const int* in_sizes, int n_in,
                              void* d_out, int out_size, void* d_ws, size_t ws_size,
                              hipStream_t stream) {
  const float* X  = (const float*)d_in[0];
  const float* Wq = (const float*)d_in[1];
  const float* Wk = (const float*)d_in[2];
  const float* Wv = (const float*)d_in[3];
  const float* Wo = (const float*)d_in[4];
  float* out = (float*)d_out;

  char* ws = (char*)d_ws;
  unsigned short* Xb    = (unsigned short*)(ws);                            // 8 MB (dead after QKV gemm)
  unsigned short* VTg   = (unsigned short*)(ws);                            // 8 MB (reuses Xb region)
  unsigned short* Wqkvb = (unsigned short*)(ws + (size_t)8  * 1024 * 1024); // 6 MB
  unsigned short* Wob   = (unsigned short*)(ws + (size_t)14 * 1024 * 1024); // 2 MB
  unsigned short* QKV   = (unsigned short*)(ws + (size_t)16 * 1024 * 1024); // 24 MB
  unsigned short* Ob    = (unsigned short*)(ws + (size_t)40 * 1024 * 1024); // 8 MB

  const int NX4 = (2 * 2048 * 1024) / 4;
  const int NW4 = (1024 * 1024) / 4;
  cast_f32_bf16<<<dim3((NX4 + 255) / 256), dim3(256), 0, stream>>>(X, Xb, NX4);
  cast_w<<<dim3((4 * NW4 + 255) / 256), dim3(256), 0, stream>>>(Wq, Wk, Wv, Wo, Wqkvb, Wob, NW4);

  gemm_bt<true ><<<dim3(32, 24), dim3(256), 0, stream>>>(Xb, Wqkvb, (void*)QKV, 4096, 3072, 1024);
  transpose_v<<<dim3(32, 32), dim3(256), 0, stream>>>(QKV, VTg);
  attn11<<<dim3(1024), dim3(256), 0, stream>>>(QKV, VTg, Ob);
  gemm_bt<false><<<dim3(32, 8), dim3(256), 0, stream>>>(Ob, Wob, (void*)out, 4096, 1024, 1024);
}